// Round 5
// baseline (23501.338 us; speedup 1.0000x reference)
//
#include <hip/hip_runtime.h>

typedef float f32x4 __attribute__((ext_vector_type(4)));
typedef short s16x8 __attribute__((ext_vector_type(8)));

#define MINI(a,b) ((a)<(b)?(a):(b))
#define MAXI(a,b) ((a)>(b)?(a):(b))

static __device__ __forceinline__ float bf2f(unsigned short u){
  union { unsigned int i; float f; } x; x.i = ((unsigned int)u) << 16; return x.f;
}
static __device__ __forceinline__ unsigned short f2bf(float f){
  union { float f; unsigned int i; } x; x.f = f;
  return (unsigned short)((x.i + 0x7fffu + ((x.i >> 16) & 1u)) >> 16);
}
static __device__ __forceinline__ float sigm(float x){ return 1.f / (1.f + __expf(-x)); }
static __device__ __forceinline__ float tanhf_(float x){ return 1.f - 2.f / (1.f + __expf(2.f * x)); }

// --- per-access agent coherence (sc1 ops at LLC; no cache-wide inv/wb) ---
static __device__ __forceinline__ float ald1(const float* p){
  return __hip_atomic_load(p, __ATOMIC_RELAXED, __HIP_MEMORY_SCOPE_AGENT);
}
static __device__ __forceinline__ void ast1(float* p, float v){
  __hip_atomic_store(p, v, __ATOMIC_RELAXED, __HIP_MEMORY_SCOPE_AGENT);
}
static __device__ __forceinline__ float2 ald2(const float* p){
  unsigned long long u = __hip_atomic_load((const unsigned long long*)p,
                          __ATOMIC_RELAXED, __HIP_MEMORY_SCOPE_AGENT);
  union { unsigned long long u; float2 f; } c; c.u = u; return c.f;
}
static __device__ __forceinline__ void ast2(float* p, float a, float b){
  union { unsigned long long u; float f[2]; } c; c.f[0] = a; c.f[1] = b;
  __hip_atomic_store((unsigned long long*)p, c.u, __ATOMIC_RELAXED, __HIP_MEMORY_SCOPE_AGENT);
}
static __device__ __forceinline__ unsigned long long ald64(const void* p){
  return __hip_atomic_load((const unsigned long long*)p, __ATOMIC_RELAXED, __HIP_MEMORY_SCOPE_AGENT);
}
static __device__ __forceinline__ void ast32(unsigned short* p, unsigned int v){
  __hip_atomic_store((unsigned int*)p, v, __ATOMIC_RELAXED, __HIP_MEMORY_SCOPE_AGENT);
}
static __device__ __forceinline__ void aadd(float* p, float v){
  __hip_atomic_fetch_add(p, v, __ATOMIC_RELAXED, __HIP_MEMORY_SCOPE_AGENT);
}

// ---------------------------------------------------------------------------
// K1: fold Wq into key projection (Bmat bf16), biases.
// ---------------------------------------------------------------------------
__global__ void k_prepw(const float* Wk, const float* Wq, const float* Wv,
                        const float* bk, const float* bq, const float* bv,
                        unsigned short* Bm, float* bvec, float* wkb, float* cb0){
  const int k = blockIdx.x;     // 512
  const int t = threadIdx.x;    // 256
  const float scale = 0.0625f;
  float acc = 0.f;
  for (int p = 0; p < 256; p++) acc += Wk[k*256+p] * Wq[t*256+p];
  Bm[(size_t)k*512 + t]       = f2bf(acc * scale);
  Bm[(size_t)k*512 + 256 + t] = f2bf(Wv[k*256+t]);
  __shared__ float red[256];
  red[t] = Wk[k*256+t] * bq[t];
  __syncthreads();
  for (int o = 128; o > 0; o >>= 1){ if (t < o) red[t] += red[t+o]; __syncthreads(); }
  if (t == 0) wkb[k] = red[0] * scale;
  if (k == 0){
    float a2 = 0.f;
    for (int p = 0; p < 256; p++) a2 += bk[p] * Wq[t*256+p];
    bvec[t] = a2 * scale;
    bvec[256+t] = bv[t];
    __syncthreads();
    red[t] = bk[t] * bq[t];
    __syncthreads();
    for (int o = 128; o > 0; o >>= 1){ if (t < o) red[t] += red[t+o]; __syncthreads(); }
    if (t == 0) *cb0 = red[0] * scale;
  }
}

__global__ void k_keybias(const float* enc, const float* wkb, const float* cb0,
                          float* keybias){
  const int m = blockIdx.x*8 + (threadIdx.x >> 6);
  const int lane = threadIdx.x & 63;
  float p = 0.f;
  #pragma unroll
  for (int j = 0; j < 8; j++){ int k = lane + 64*j; p += enc[(size_t)m*512 + k] * wkb[k]; }
  #pragma unroll
  for (int o = 1; o < 64; o <<= 1) p += __shfl_xor(p, o, 64);
  if (lane == 0) keybias[m] = p + *cb0;
}

// ---------------------------------------------------------------------------
// K3: init: ctx(parity0)=key_proj[:,0,:] f32, l=1, zero h1/h2/c1/c2/ctrs.
// ---------------------------------------------------------------------------
__global__ void k_init(const float* enc, const float* Wk, const float* bk,
                       float* ctx, float* la, unsigned short* h1bf,
                       unsigned short* h2bf, float* h2f, float* c1p, float* c2p,
                       unsigned int* ctr){
  const int b = blockIdx.x, t = threadIdx.x;  // 64 x 256
  float acc = bk[t];
  const float* er = enc + (size_t)b*800*512;
  for (int k = 0; k < 512; k++) acc += er[k] * Wk[(size_t)k*256 + t];
  ctx[b*256 + t] = acc;
  if (t == 0) la[b] = 1.f;
  const int id = b*256 + t;           // 0..16383
  unsigned int* h1u = (unsigned int*)h1bf;   // 32768 uints (2 bufs)
  h1u[id] = 0u; h1u[16384 + id] = 0u;
  unsigned int* h2u = (unsigned int*)h2bf;   // 16384 uints (2 bufs)
  h2u[id] = 0u;
  h2f[id] = 0.f; h2f[16384 + id] = 0.f;
  c1p[id] = 0.f; c1p[16384 + id] = 0.f;      // 256 blocks * 128
  c2p[id] = 0.f;                             // 128 blocks * 128
  if (b == 0){ for (int i = t; i < 1024; i += 256) ctr[i] = 0u; }
}

// ---------------------------------------------------------------------------
// K4: MFMA bf16 GEMM; epilogue scatters to keyT[b][k][s] and val[b][s][d].
// ---------------------------------------------------------------------------
__global__ __launch_bounds__(256) void k_gemm(const float* enc, const unsigned short* Bm,
                                              const float* bvec,
                                              unsigned short* kT, unsigned short* vl){
  __shared__ unsigned short Al[64][40];
  __shared__ unsigned short Bl[64][40];
  const int tid = threadIdx.x, w = tid >> 6, lane = tid & 63;
  const int M0 = (blockIdx.x >> 3) * 64;
  const int N0 = (blockIdx.x & 7) * 64;
  f32x4 acc[4] = {};
  const int mrow = w*16 + (lane & 15);
  const int koff = (lane >> 4) * 8;
  for (int k0 = 0; k0 < 512; k0 += 32){
    #pragma unroll
    for (int it = 0; it < 2; it++){
      int row = (tid >> 3) + it*32, kq = (tid & 7) * 4;
      float4 v = *(const float4*)(enc + (size_t)(M0+row)*512 + k0 + kq);
      Al[row][kq+0] = f2bf(v.x); Al[row][kq+1] = f2bf(v.y);
      Al[row][kq+2] = f2bf(v.z); Al[row][kq+3] = f2bf(v.w);
    }
    #pragma unroll
    for (int i = 0; i < 8; i++){
      int flat = tid*8 + i, kk = flat >> 6, n = flat & 63;
      Bl[n][kk] = Bm[(size_t)(k0+kk)*512 + N0 + n];
    }
    __syncthreads();
    s16x8 a = *(const s16x8*)&Al[mrow][koff];
    #pragma unroll
    for (int i = 0; i < 4; i++){
      s16x8 bb = *(const s16x8*)&Bl[i*16 + (lane & 15)][koff];
      acc[i] = __builtin_amdgcn_mfma_f32_16x16x32_bf16(a, bb, acc[i], 0, 0, 0);
    }
    __syncthreads();
  }
  #pragma unroll
  for (int i = 0; i < 4; i++){
    int n = N0 + i*16 + (lane & 15);
    float bb = bvec[n];
    #pragma unroll
    for (int r = 0; r < 4; r++){
      int m = M0 + w*16 + (lane >> 4)*4 + r;
      int b = m / 800, s = m - b*800;
      unsigned short hv = f2bf(acc[i][r] + bb);
      if (n < 256) kT[(size_t)b*204800 + (size_t)n*800 + s] = hv;
      else         vl[(size_t)b*204800 + (size_t)s*256 + (n-256)] = hv;
    }
  }
}

// ---------------------------------------------------------------------------
// Grid barrier: relaxed arrival (16 spread lines) + relaxed poll. No fences.
// ---------------------------------------------------------------------------
static __device__ __forceinline__ void gbar(unsigned int* ctrs, unsigned int* gen){
  __syncthreads();
  if (threadIdx.x == 0){
    *gen += 256u;
    __hip_atomic_fetch_add(&ctrs[(blockIdx.x & 15) * 32], 1u,
                           __ATOMIC_RELAXED, __HIP_MEMORY_SCOPE_AGENT);
    const unsigned int target = *gen;
    for (;;){
      unsigned int s = 0;
      #pragma unroll
      for (int i = 0; i < 16; i++)
        s += __hip_atomic_load(&ctrs[i * 32], __ATOMIC_RELAXED, __HIP_MEMORY_SCOPE_AGENT);
      if (s >= target) break;
      __builtin_amdgcn_s_sleep(1);
    }
  }
  __syncthreads();
}

// ---------------------------------------------------------------------------
// Pipelined dot helpers: 32-dim chunks, one-chunk lookahead (loads issued
// before current chunk's FMAs -> 8-16 sc1 loads always in flight).
// ---------------------------------------------------------------------------
static __device__ __forceinline__ void dot_bf16(const unsigned short* xg, int k0, int k1,
                                                const float (*W)[8], float* acc){
  if (k0 >= k1) return;
  const int nch = (k1 - k0) >> 5;
  const unsigned long long* p = (const unsigned long long*)(xg + k0);
  unsigned long long cur[8], nxt[8];
  #pragma unroll
  for (int i = 0; i < 8; i++) cur[i] = ald64(p + i);
  for (int c = 0; c < nch; c++){
    const bool more = (c + 1 < nch);
    if (more){
      const unsigned long long* pn = p + (c + 1) * 8;
      #pragma unroll
      for (int i = 0; i < 8; i++) nxt[i] = ald64(pn + i);
    }
    const int kb = k0 + c * 32;
    #pragma unroll
    for (int i = 0; i < 8; i++){
      float xv[4];
      xv[0] = bf2f((unsigned short)cur[i]);
      xv[1] = bf2f((unsigned short)(cur[i] >> 16));
      xv[2] = bf2f((unsigned short)(cur[i] >> 32));
      xv[3] = bf2f((unsigned short)(cur[i] >> 48));
      #pragma unroll
      for (int d = 0; d < 4; d++){
        const float* wr = W[kb + i*4 + d];
        #pragma unroll
        for (int cc = 0; cc < 8; cc++) acc[cc] += xv[d] * wr[cc];
      }
    }
    if (more){
      #pragma unroll
      for (int i = 0; i < 8; i++) cur[i] = nxt[i];
    }
  }
}

static __device__ __forceinline__ void dot_f32(const float* xg, int k0, int k1,
                                               const float (*W)[8], float* acc){
  if (k0 >= k1) return;
  const int nch = (k1 - k0) >> 5;
  const float* p = xg + k0;
  float2 cur[16], nxt[16];
  #pragma unroll
  for (int i = 0; i < 16; i++) cur[i] = ald2(p + 2*i);
  for (int c = 0; c < nch; c++){
    const bool more = (c + 1 < nch);
    if (more){
      const float* pn = p + (c + 1) * 32;
      #pragma unroll
      for (int i = 0; i < 16; i++) nxt[i] = ald2(pn + 2*i);
    }
    const int kb = k0 + c * 32;
    #pragma unroll
    for (int i = 0; i < 16; i++){
      const float* w0 = W[kb + 2*i];
      const float* w1 = W[kb + 2*i + 1];
      #pragma unroll
      for (int cc = 0; cc < 8; cc++) acc[cc] += cur[i].x * w0[cc];
      #pragma unroll
      for (int cc = 0; cc < 8; cc++) acc[cc] += cur[i].y * w1[cc];
    }
    if (more){
      #pragma unroll
      for (int i = 0; i < 16; i++) cur[i] = nxt[i];
    }
  }
}

__global__ __launch_bounds__(512) void k_decode(
    const float* W_ih1, const float* b_ih1, const float* W_hh1, const float* b_hh1,
    const float* W_ih2, const float* b_ih2, const float* W_hh2, const float* b_hh2,
    const float* embW, const float* char_b, const int* lens, const int* y,
    const unsigned short* kT, const unsigned short* vl, const float* keybias,
    unsigned short* h1bf, unsigned short* h2bf, float* h2f,
    float* ctxacc, float* lacc, float* c1p, float* c2p,
    float* esc, unsigned int* ctr, float* out)
{
  __shared__ float W1s[1280][8];   // 40 KB: 8 gate1 cols (dims 2bi,2bi+1)
  __shared__ float W2s[768][8];    // 24 KB: 8 gate2 cols (dims 2bi,2bi+1), bi<128
  __shared__ float b1s[8];
  __shared__ float b2s[8];
  __shared__ float embrow[512];
  __shared__ float chb;
  __shared__ float redA[8][8][64];
  __shared__ float g1s[8][64];
  __shared__ float part[2][256];
  __shared__ float e_l[256];
  __shared__ float h2loc[256];

  const int bi = blockIdx.x;
  const int tid = threadIdx.x;
  const int w = tid >> 6;
  const int lane = tid & 63;

  for (int idx = tid; idx < 1280*8; idx += 512){
    int k = idx >> 3, c = idx & 7;
    int col = ((c >> 1) << 9) + 2*bi + (c & 1);
    W1s[k][c] = (k < 768) ? W_ih1[(size_t)k*2048 + col] : W_hh1[(size_t)(k-768)*2048 + col];
  }
  if (bi < 128){
    for (int idx = tid; idx < 768*8; idx += 512){
      int k = idx >> 3, c = idx & 7;
      int col = ((c >> 1) << 8) + 2*bi + (c & 1);
      W2s[k][c] = (k < 512) ? W_ih2[(size_t)k*1024 + col] : W_hh2[(size_t)(k-512)*1024 + col];
    }
    if (tid < 8){ int col = ((tid >> 1) << 8) + 2*bi + (tid & 1); b2s[tid] = b_ih2[col] + b_hh2[col]; }
  }
  if (tid < 8){ int col = ((tid >> 1) << 9) + 2*bi + (tid & 1); b1s[tid] = b_ih1[col] + b_hh1[col]; }
  if (bi >= 128 && bi < 158){
    embrow[tid] = embW[(bi-128)*512 + tid];
    if (tid == 0) chb = char_b[bi-128];
  }
  __syncthreads();

  unsigned int gen = 0;
  const int myb = bi & 63;
  const int sc  = bi >> 6;
  const int mylen = lens[myb];
  const int sbase = sc * 200;

  float* preds = out;            // [64][250][30]
  float* plot  = out + 480000;   // [800][250]

  for (int t = 0; t < 250; ++t){
    const int p  = t & 1;
    const int np = 1 - p;
    const unsigned short* h1p_bf = h1bf + p*(64*512);
    unsigned short*       h1n_bf = h1bf + np*(64*512);
    const unsigned short* h2p_bf = h2bf + p*(64*256);
    unsigned short*       h2n_bf = h2bf + np*(64*256);
    const float* h2f_p = h2f + p*(64*256);
    float*       h2f_np= h2f + np*(64*256);
    const float* ca_p  = ctxacc + p*(64*256);
    float*       ca_np = ctxacc + np*(64*256);
    const float* la_p  = lacc + p*64;
    float*       la_np = lacc + np*64;

    // ---------------- Phase 1: gates1 + LSTM1 (all 256 blocks) ----------------
    {
      float acc[8]  = {0,0,0,0,0,0,0,0};
      float accB[8] = {0,0,0,0,0,0,0,0};
      const int b = lane;
      const int tok = (t == 0) ? 0 : y[b*250 + (t-1)];
      const float* erow = embW + (size_t)tok*512;            // plain cached
      const float* crow = ca_p + b*256 - 512;                // f32 sc1
      const unsigned short* hrow = h1p_bf + b*512 - 768;     // bf16 sc1
      const int k0 = w*160, k1 = k0 + 160;
      const int a1 = MINI(k1, 512);
      for (int k = k0; k < a1; k += 4){
        float4 xv = *(const float4*)(erow + k);
        const float* w0 = W1s[k]; const float* w1 = W1s[k+1];
        const float* w2 = W1s[k+2]; const float* w3 = W1s[k+3];
        #pragma unroll
        for (int cc = 0; cc < 8; cc++)
          acc[cc] += xv.x*w0[cc] + xv.y*w1[cc] + xv.z*w2[cc] + xv.w*w3[cc];
      }
      dot_f32(crow, MAXI(k0,512), MINI(k1,768), W1s, accB);
      dot_bf16(hrow, MAXI(k0,768), k1, W1s, acc);
      const float rl = 1.f / ald1(&la_p[b]);
      #pragma unroll
      for (int c = 0; c < 8; c++) redA[w][c][b] = acc[c] + accB[c]*rl;
    }
    __syncthreads();
    { int c = tid >> 6, b = tid & 63;
      float g = b1s[c];
      #pragma unroll
      for (int ww = 0; ww < 8; ww++) g += redA[ww][c][b];
      g1s[c][b] = g;
    }
    __syncthreads();
    if (w == 0){   // LSTM1 cell: dims 2bi, 2bi+1
      int b = lane;
      float h0, h1v;
      { float gi=g1s[0][b], gf=g1s[2][b], gg=g1s[4][b], go=g1s[6][b];
        float co = c1p[bi*128 + 2*b];
        float cn = sigm(gf)*co + sigm(gi)*tanhf_(gg);
        c1p[bi*128 + 2*b] = cn; h0 = sigm(go)*tanhf_(cn); }
      { float gi=g1s[1][b], gf=g1s[3][b], gg=g1s[5][b], go=g1s[7][b];
        float co = c1p[bi*128 + 2*b + 1];
        float cn = sigm(gf)*co + sigm(gi)*tanhf_(gg);
        c1p[bi*128 + 2*b + 1] = cn; h1v = sigm(go)*tanhf_(cn); }
      unsigned int pk = (unsigned int)f2bf(h0) | ((unsigned int)f2bf(h1v) << 16);
      ast32(h1n_bf + b*512 + 2*bi, pk);
    }
    gbar(ctr, &gen);  // SYNC1: h1 ready

    // ---------------- Phase 2 (split by block role) ----------------
    if (bi < 128){
      // gates2 + LSTM2: dims 2bi, 2bi+1
      {
        float acc2[8] = {0,0,0,0,0,0,0,0};
        const int b = lane;
        const unsigned short* h1r = h1n_bf + b*512;
        const unsigned short* h2r = h2p_bf + b*256 - 512;
        const int k0 = w*96, k1 = k0 + 96;
        dot_bf16(h1r, k0, MINI(k1,512), W2s, acc2);
        dot_bf16(h2r, MAXI(k0,512), k1, W2s, acc2);
        #pragma unroll
        for (int c = 0; c < 8; c++) redA[w][c][lane] = acc2[c];
      }
      __syncthreads();
      { int c = tid >> 6, b = tid & 63;
        float g = b2s[c];
        #pragma unroll
        for (int ww = 0; ww < 8; ww++) g += redA[ww][c][b];
        g1s[c][b] = g;
      }
      __syncthreads();
      if (w == 0){
        int b = lane;
        float h0, h1v;
        { float gi=g1s[0][b], gf=g1s[2][b], gg=g1s[4][b], go=g1s[6][b];
          float co = c2p[bi*128 + 2*b];
          float cn = sigm(gf)*co + sigm(gi)*tanhf_(gg);
          c2p[bi*128 + 2*b] = cn; h0 = sigm(go)*tanhf_(cn); }
        { float gi=g1s[1][b], gf=g1s[3][b], gg=g1s[5][b], go=g1s[7][b];
          float co = c2p[bi*128 + 2*b + 1];
          float cn = sigm(gf)*co + sigm(gi)*tanhf_(gg);
          c2p[bi*128 + 2*b + 1] = cn; h1v = sigm(go)*tanhf_(cn); }
        unsigned int pk = (unsigned int)f2bf(h0) | ((unsigned int)f2bf(h1v) << 16);
        ast32(h2n_bf + b*256 + 2*bi, pk);
        ast2(h2f_np + b*256 + 2*bi, h0, h1v);
      }
    } else if (bi < 158){
      // logits for step t-1
      if (t > 0){
        int b3 = tid & 63, ch = tid >> 6;
        const float* base = (ch < 4) ? (h2f_p + b3*256 + ch*64)
                                     : (ca_p  + b3*256 + (ch-4)*64);
        const float* er = &embrow[(ch < 4) ? ch*64 : 256 + (ch-4)*64];
        float2 v[32];
        #pragma unroll
        for (int i = 0; i < 32; i++) v[i] = ald2(base + 2*i);
        float pc = 0.f;
        #pragma unroll
        for (int i = 0; i < 32; i++) pc += v[i].x*er[2*i] + v[i].y*er[2*i+1];
        if (ch >= 4) pc *= 1.f / ald1(&la_p[b3]);
        g1s[ch][b3] = pc;
        __syncthreads();
        if (tid < 64){
          float s2 = chb;
          #pragma unroll
          for (int c = 0; c < 8; c++) s2 += g1s[c][tid];
          preds[tid*7500 + (t-1)*30 + (bi-128)] = s2;
        }
      }
    } else if (bi < 190){
      if (t > 0 && tid < 25){
        int s3 = (bi-158)*25 + tid;
        plot[(size_t)s3*250 + (t-1)] = ald1(&esc[s3]) * (1.f / ald1(&la_p[0]));
      }
    } else if (bi < 254){
      if (tid < 128) ast2(&ca_np[(bi-190)*256 + 2*tid], 0.f, 0.f);
    } else if (bi == 254){
      if (tid < 64) ast1(&la_np[tid], 0.f);
    }
    gbar(ctr, &gen);  // SYNC2: h2 ready, accumulators zeroed

    // ---------------- Phase 3: attention (all blocks; s-quarter) ----------------
    {
      if (tid < 128){ float2 hv = ald2(&h2f_np[myb*256 + 2*tid]);
                      h2loc[2*tid] = hv.x; h2loc[2*tid+1] = hv.y; }
      __syncthreads();
      const int qlen = MINI(200, MAXI(0, mylen - sbase));
      const int srow = tid & 255, kh = tid >> 8;
      if (srow < qlen){
        const unsigned short* kp = kT + (size_t)myb*204800 + (size_t)(kh*128)*800 + sbase + srow;
        const float* hl = &h2loc[kh*128];
        float pacc = 0.f;
        #pragma unroll 4
        for (int k = 0; k < 128; k++){ pacc += bf2f(*kp)*hl[k]; kp += 800; }
        part[kh][srow] = pacc;
      }
      __syncthreads();
      if (tid < 256){
        float e = 0.f;
        if (tid < qlen) e = __expf(part[0][tid] + part[1][tid] + keybias[myb*800 + sbase + tid]);
        e_l[tid] = e;
        if (myb == 0 && tid < 200) ast1(&esc[sbase + tid], e);
      }
      __syncthreads();
      if (w == 0){
        float s4 = e_l[lane] + e_l[lane+64] + e_l[lane+128] + e_l[lane+192];
        #pragma unroll
        for (int o = 1; o < 64; o <<= 1) s4 += __shfl_xor(s4, o, 64);
        if (lane == 0) aadd(&la_np[myb], s4);
      }
      {
        const int d = tid & 255, rh = tid >> 8;
        const int j0 = rh*100, j1 = MINI(j0+100, qlen);
        float a = 0.f;
        const unsigned short* vp = vl + (size_t)myb*204800 + (size_t)(sbase+j0)*256 + d;
        #pragma unroll 4
        for (int j = j0; j < j1; j++){ a += e_l[j]*bf2f(*vp); vp += 256; }
        part[rh][d] = a;
      }
      __syncthreads();
      if (tid < 256) aadd(&ca_np[myb*256 + tid], part[0][tid] + part[1][tid]);
    }
    gbar(ctr, &gen);  // SYNC3: context accumulated
  }

  // ---------------- epilogue: outputs for step 249 (parity 0 buffers) ----------------
  {
    const float* h2f_p = h2f;        // parity 0
    const float* ca_p  = ctxacc;
    const float* la_p  = lacc;
    if (bi >= 128 && bi < 158){
      int b3 = tid & 63, ch = tid >> 6;
      const float* base = (ch < 4) ? (h2f_p + b3*256 + ch*64)
                                   : (ca_p  + b3*256 + (ch-4)*64);
      const float* er = &embrow[(ch < 4) ? ch*64 : 256 + (ch-4)*64];
      float2 v[32];
      #pragma unroll
      for (int i = 0; i < 32; i++) v[i] = ald2(base + 2*i);
      float pc = 0.f;
      #pragma unroll
      for (int i = 0; i < 32; i++) pc += v[i].x*er[2*i] + v[i].y*er[2*i+1];
      if (ch >= 4) pc *= 1.f / ald1(&la_p[b3]);
      g1s[ch][b3] = pc;
      __syncthreads();
      if (tid < 64){
        float s2 = chb;
        #pragma unroll
        for (int c = 0; c < 8; c++) s2 += g1s[c][tid];
        preds[tid*7500 + 249*30 + (bi-128)] = s2;
      }
    } else if (bi >= 158 && bi < 190){
      if (tid < 25){
        int s3 = (bi-158)*25 + tid;
        plot[(size_t)s3*250 + 249] = ald1(&esc[s3]) * (1.f / ald1(&la_p[0]));
      }
    }
  }
}

// ---------------------------------------------------------------------------
extern "C" void kernel_launch(void* const* d_in, const int* in_sizes, int n_in,
                              void* d_out, int out_size, void* d_ws, size_t ws_size,
                              hipStream_t stream){
  const float* enc    = (const float*)d_in[0];
  const float* embW   = (const float*)d_in[1];
  const float* W_ih1  = (const float*)d_in[2];
  const float* b_ih1  = (const float*)d_in[3];
  const float* W_hh1  = (const float*)d_in[4];
  const float* b_hh1  = (const float*)d_in[5];
  const float* W_ih2  = (const float*)d_in[6];
  const float* b_ih2  = (const float*)d_in[7];
  const float* W_hh2  = (const float*)d_in[8];
  const float* b_hh2  = (const float*)d_in[9];
  const float* Wk     = (const float*)d_in[10];
  const float* bk     = (const float*)d_in[11];
  const float* Wv     = (const float*)d_in[12];
  const float* bv     = (const float*)d_in[13];
  const float* Wq     = (const float*)d_in[14];
  const float* bq     = (const float*)d_in[15];
  const float* char_b = (const float*)d_in[16];
  const int*   lens   = (const int*)d_in[17];
  const int*   y      = (const int*)d_in[18];

  char* ws = (char*)d_ws;
  unsigned short* kT   = (unsigned short*)(ws + 0);          // 26,214,400
  unsigned short* vlp  = (unsigned short*)(ws + 26214400);   // 26,214,400
  float* keybias       = (float*)(ws + 52428800);            //    204,800
  unsigned short* Bmat = (unsigned short*)(ws + 52633600);   //    524,288
  float* bvec          = (float*)(ws + 53157888);            //      2,048
  float* wkb           = (float*)(ws + 53159936);            //      2,048
  float* cb0           = (float*)(ws + 53161984);            //      1,024
  unsigned short* h1bf = (unsigned short*)(ws + 53163008);   //    131,072 (2 bufs)
  unsigned short* h2bf = (unsigned short*)(ws + 53294080);   //     65,536 (2 bufs)
  float* h2f           = (float*)(ws + 53359616);            //    262,144 (2 bufs)
  float* ctxacc        = (float*)(ws + 53621760);            //    131,072 (2 bufs)
  float* lacc          = (float*)(ws + 53752832);            //      1,024 (2 bufs)
  float* c1p           = (float*)(ws + 53753856);            //    131,072
  float* c2p           = (float*)(ws + 53884928);            //     65,536
  float* esc           = (float*)(ws + 53950464);            //      4,096
  unsigned int* ctr    = (unsigned int*)(ws + 53954560);     //      4,096
  float* out = (float*)d_out;

  k_prepw<<<512, 256, 0, stream>>>(Wk, Wq, Wv, bk, bq, bv, Bmat, bvec, wkb, cb0);
  k_keybias<<<6400, 512, 0, stream>>>(enc, wkb, cb0, keybias);
  k_init<<<64, 256, 0, stream>>>(enc, Wk, bk, ctxacc, lacc, h1bf, h2bf, h2f, c1p, c2p, ctr);
  k_gemm<<<6400, 256, 0, stream>>>(enc, Bmat, bvec, kT, vlp);
  k_decode<<<256, 512, 0, stream>>>(W_ih1, b_ih1, W_hh1, b_hh1, W_ih2, b_ih2, W_hh2, b_hh2,
                                    embW, char_b, lens, y, kT, vlp, keybias,
                                    h1bf, h2bf, h2f, ctxacc, lacc, c1p, c2p, esc, ctr, out);
}

// Round 6
// 22363.068 us; speedup vs baseline: 1.0509x; 1.0509x over previous
//
#include <hip/hip_runtime.h>

typedef float f32x4 __attribute__((ext_vector_type(4)));
typedef short s16x8 __attribute__((ext_vector_type(8)));

#define MINI(a,b) ((a)<(b)?(a):(b))
#define MAXI(a,b) ((a)>(b)?(a):(b))

static __device__ __forceinline__ float bf2f(unsigned short u){
  union { unsigned int i; float f; } x; x.i = ((unsigned int)u) << 16; return x.f;
}
static __device__ __forceinline__ unsigned short f2bf(float f){
  union { float f; unsigned int i; } x; x.f = f;
  return (unsigned short)((x.i + 0x7fffu + ((x.i >> 16) & 1u)) >> 16);
}
static __device__ __forceinline__ float sigm(float x){ return 1.f / (1.f + __expf(-x)); }
static __device__ __forceinline__ float tanhf_(float x){ return 1.f - 2.f / (1.f + __expf(2.f * x)); }

// --- per-access agent coherence (sc1 ops at LLC; no cache-wide inv/wb) ---
static __device__ __forceinline__ float ald1(const float* p){
  return __hip_atomic_load(p, __ATOMIC_RELAXED, __HIP_MEMORY_SCOPE_AGENT);
}
static __device__ __forceinline__ void ast1(float* p, float v){
  __hip_atomic_store(p, v, __ATOMIC_RELAXED, __HIP_MEMORY_SCOPE_AGENT);
}
static __device__ __forceinline__ float2 ald2(const float* p){
  unsigned long long u = __hip_atomic_load((const unsigned long long*)p,
                          __ATOMIC_RELAXED, __HIP_MEMORY_SCOPE_AGENT);
  union { unsigned long long u; float2 f; } c; c.u = u; return c.f;
}
static __device__ __forceinline__ void ast2(float* p, float a, float b){
  union { unsigned long long u; float f[2]; } c; c.f[0] = a; c.f[1] = b;
  __hip_atomic_store((unsigned long long*)p, c.u, __ATOMIC_RELAXED, __HIP_MEMORY_SCOPE_AGENT);
}
static __device__ __forceinline__ unsigned long long ald64(const void* p){
  return __hip_atomic_load((const unsigned long long*)p, __ATOMIC_RELAXED, __HIP_MEMORY_SCOPE_AGENT);
}
static __device__ __forceinline__ void ast32(unsigned short* p, unsigned int v){
  __hip_atomic_store((unsigned int*)p, v, __ATOMIC_RELAXED, __HIP_MEMORY_SCOPE_AGENT);
}
static __device__ __forceinline__ void aadd(float* p, float v){
  __hip_atomic_fetch_add(p, v, __ATOMIC_RELAXED, __HIP_MEMORY_SCOPE_AGENT);
}

// ---------------------------------------------------------------------------
// K1: fold Wq into key projection (Bmat bf16), biases.
// ---------------------------------------------------------------------------
__global__ void k_prepw(const float* Wk, const float* Wq, const float* Wv,
                        const float* bk, const float* bq, const float* bv,
                        unsigned short* Bm, float* bvec, float* wkb, float* cb0){
  const int k = blockIdx.x;     // 512
  const int t = threadIdx.x;    // 256
  const float scale = 0.0625f;
  float acc = 0.f;
  for (int p = 0; p < 256; p++) acc += Wk[k*256+p] * Wq[t*256+p];
  Bm[(size_t)k*512 + t]       = f2bf(acc * scale);
  Bm[(size_t)k*512 + 256 + t] = f2bf(Wv[k*256+t]);
  __shared__ float red[256];
  red[t] = Wk[k*256+t] * bq[t];
  __syncthreads();
  for (int o = 128; o > 0; o >>= 1){ if (t < o) red[t] += red[t+o]; __syncthreads(); }
  if (t == 0) wkb[k] = red[0] * scale;
  if (k == 0){
    float a2 = 0.f;
    for (int p = 0; p < 256; p++) a2 += bk[p] * Wq[t*256+p];
    bvec[t] = a2 * scale;
    bvec[256+t] = bv[t];
    __syncthreads();
    red[t] = bk[t] * bq[t];
    __syncthreads();
    for (int o = 128; o > 0; o >>= 1){ if (t < o) red[t] += red[t+o]; __syncthreads(); }
    if (t == 0) *cb0 = red[0] * scale;
  }
}

__global__ void k_keybias(const float* enc, const float* wkb, const float* cb0,
                          float* keybias){
  const int m = blockIdx.x*8 + (threadIdx.x >> 6);
  const int lane = threadIdx.x & 63;
  float p = 0.f;
  #pragma unroll
  for (int j = 0; j < 8; j++){ int k = lane + 64*j; p += enc[(size_t)m*512 + k] * wkb[k]; }
  #pragma unroll
  for (int o = 1; o < 64; o <<= 1) p += __shfl_xor(p, o, 64);
  if (lane == 0) keybias[m] = p + *cb0;
}

// ---------------------------------------------------------------------------
// K3: init: ctx(parity0)=key_proj[:,0,:] f32, l=1, zero h1/h2/c1/c2/ctrs.
// ---------------------------------------------------------------------------
__global__ void k_init(const float* enc, const float* Wk, const float* bk,
                       float* ctx, float* la, unsigned short* h1bf,
                       unsigned short* h2bf, float* h2f, float* c1p, float* c2p,
                       unsigned int* ctr){
  const int b = blockIdx.x, t = threadIdx.x;  // 64 x 256
  float acc = bk[t];
  const float* er = enc + (size_t)b*800*512;
  for (int k = 0; k < 512; k++) acc += er[k] * Wk[(size_t)k*256 + t];
  ctx[b*256 + t] = acc;
  if (t == 0) la[b] = 1.f;
  const int id = b*256 + t;           // 0..16383
  unsigned int* h1u = (unsigned int*)h1bf;   // 32768 uints (2 bufs)
  h1u[id] = 0u; h1u[16384 + id] = 0u;
  unsigned int* h2u = (unsigned int*)h2bf;   // 16384 uints (2 bufs)
  h2u[id] = 0u;
  h2f[id] = 0.f; h2f[16384 + id] = 0.f;
  c1p[id] = 0.f; c1p[16384 + id] = 0.f;      // 256 blocks * 128
  c2p[id] = 0.f;                             // 128 blocks * 128
  if (b == 0){ for (int i = t; i < 1024; i += 256) ctr[i] = 0u; }
}

// ---------------------------------------------------------------------------
// K4: MFMA bf16 GEMM; epilogue scatters to keyT[b][k][s] and val[b][s][d].
// ---------------------------------------------------------------------------
__global__ __launch_bounds__(256) void k_gemm(const float* enc, const unsigned short* Bm,
                                              const float* bvec,
                                              unsigned short* kT, unsigned short* vl){
  __shared__ unsigned short Al[64][40];
  __shared__ unsigned short Bl[64][40];
  const int tid = threadIdx.x, w = tid >> 6, lane = tid & 63;
  const int M0 = (blockIdx.x >> 3) * 64;
  const int N0 = (blockIdx.x & 7) * 64;
  f32x4 acc[4] = {};
  const int mrow = w*16 + (lane & 15);
  const int koff = (lane >> 4) * 8;
  for (int k0 = 0; k0 < 512; k0 += 32){
    #pragma unroll
    for (int it = 0; it < 2; it++){
      int row = (tid >> 3) + it*32, kq = (tid & 7) * 4;
      float4 v = *(const float4*)(enc + (size_t)(M0+row)*512 + k0 + kq);
      Al[row][kq+0] = f2bf(v.x); Al[row][kq+1] = f2bf(v.y);
      Al[row][kq+2] = f2bf(v.z); Al[row][kq+3] = f2bf(v.w);
    }
    #pragma unroll
    for (int i = 0; i < 8; i++){
      int flat = tid*8 + i, kk = flat >> 6, n = flat & 63;
      Bl[n][kk] = Bm[(size_t)(k0+kk)*512 + N0 + n];
    }
    __syncthreads();
    s16x8 a = *(const s16x8*)&Al[mrow][koff];
    #pragma unroll
    for (int i = 0; i < 4; i++){
      s16x8 bb = *(const s16x8*)&Bl[i*16 + (lane & 15)][koff];
      acc[i] = __builtin_amdgcn_mfma_f32_16x16x32_bf16(a, bb, acc[i], 0, 0, 0);
    }
    __syncthreads();
  }
  #pragma unroll
  for (int i = 0; i < 4; i++){
    int n = N0 + i*16 + (lane & 15);
    float bb = bvec[n];
    #pragma unroll
    for (int r = 0; r < 4; r++){
      int m = M0 + w*16 + (lane >> 4)*4 + r;
      int b = m / 800, s = m - b*800;
      unsigned short hv = f2bf(acc[i][r] + bb);
      if (n < 256) kT[(size_t)b*204800 + (size_t)n*800 + s] = hv;
      else         vl[(size_t)b*204800 + (size_t)s*256 + (n-256)] = hv;
    }
  }
}

// ---------------------------------------------------------------------------
// Leader/flag grid barrier. Arrivals: 1 relaxed add per block over 16 lines.
// ONLY block 0 polls the counter lines; it publishes the generation to a flag
// word; all other blocks poll just the flag line (pure reads, paced).
// No fences, no cache-wide maintenance anywhere.
// ---------------------------------------------------------------------------
static __device__ __forceinline__ void gbar(unsigned int* ctrs, unsigned int* gen){
  __syncthreads();   // drains vmcnt(0): this block's sc1 stores are at LLC
  if (threadIdx.x == 0){
    *gen += 256u;
    const unsigned int target = *gen;
    __hip_atomic_fetch_add(&ctrs[(blockIdx.x & 15) * 32], 1u,
                           __ATOMIC_RELAXED, __HIP_MEMORY_SCOPE_AGENT);
    if (blockIdx.x == 0){
      for (;;){
        unsigned int s = 0;
        #pragma unroll
        for (int i = 0; i < 16; i++)
          s += __hip_atomic_load(&ctrs[i * 32], __ATOMIC_RELAXED, __HIP_MEMORY_SCOPE_AGENT);
        if (s >= target) break;
        __builtin_amdgcn_s_sleep(2);
      }
      __hip_atomic_store(&ctrs[512], target, __ATOMIC_RELAXED, __HIP_MEMORY_SCOPE_AGENT);
    } else {
      while (__hip_atomic_load(&ctrs[512], __ATOMIC_RELAXED, __HIP_MEMORY_SCOPE_AGENT) < target)
        __builtin_amdgcn_s_sleep(4);
    }
  }
  __syncthreads();
}

// ---------------------------------------------------------------------------
// Pipelined dot helpers: 32-dim chunks, one-chunk lookahead.
// ---------------------------------------------------------------------------
static __device__ __forceinline__ void dot_bf16(const unsigned short* xg, int k0, int k1,
                                                const float (*W)[8], float* acc){
  if (k0 >= k1) return;
  const int nch = (k1 - k0) >> 5;
  const unsigned long long* p = (const unsigned long long*)(xg + k0);
  unsigned long long cur[8], nxt[8];
  #pragma unroll
  for (int i = 0; i < 8; i++) cur[i] = ald64(p + i);
  for (int c = 0; c < nch; c++){
    const bool more = (c + 1 < nch);
    if (more){
      const unsigned long long* pn = p + (c + 1) * 8;
      #pragma unroll
      for (int i = 0; i < 8; i++) nxt[i] = ald64(pn + i);
    }
    const int kb = k0 + c * 32;
    #pragma unroll
    for (int i = 0; i < 8; i++){
      float xv[4];
      xv[0] = bf2f((unsigned short)cur[i]);
      xv[1] = bf2f((unsigned short)(cur[i] >> 16));
      xv[2] = bf2f((unsigned short)(cur[i] >> 32));
      xv[3] = bf2f((unsigned short)(cur[i] >> 48));
      #pragma unroll
      for (int d = 0; d < 4; d++){
        const float* wr = W[kb + i*4 + d];
        #pragma unroll
        for (int cc = 0; cc < 8; cc++) acc[cc] += xv[d] * wr[cc];
      }
    }
    if (more){
      #pragma unroll
      for (int i = 0; i < 8; i++) cur[i] = nxt[i];
    }
  }
}

static __device__ __forceinline__ void dot_f32(const float* xg, int k0, int k1,
                                               const float (*W)[8], float* acc){
  if (k0 >= k1) return;
  const int nch = (k1 - k0) >> 5;
  const float* p = xg + k0;
  float2 cur[16], nxt[16];
  #pragma unroll
  for (int i = 0; i < 16; i++) cur[i] = ald2(p + 2*i);
  for (int c = 0; c < nch; c++){
    const bool more = (c + 1 < nch);
    if (more){
      const float* pn = p + (c + 1) * 32;
      #pragma unroll
      for (int i = 0; i < 16; i++) nxt[i] = ald2(pn + 2*i);
    }
    const int kb = k0 + c * 32;
    #pragma unroll
    for (int i = 0; i < 16; i++){
      const float* w0 = W[kb + 2*i];
      const float* w1 = W[kb + 2*i + 1];
      #pragma unroll
      for (int cc = 0; cc < 8; cc++) acc[cc] += cur[i].x * w0[cc];
      #pragma unroll
      for (int cc = 0; cc < 8; cc++) acc[cc] += cur[i].y * w1[cc];
    }
    if (more){
      #pragma unroll
      for (int i = 0; i < 16; i++) cur[i] = nxt[i];
    }
  }
}

__global__ __launch_bounds__(512) void k_decode(
    const float* W_ih1, const float* b_ih1, const float* W_hh1, const float* b_hh1,
    const float* W_ih2, const float* b_ih2, const float* W_hh2, const float* b_hh2,
    const float* embW, const float* char_b, const int* lens, const int* y,
    const unsigned short* kT, const unsigned short* vl, const float* keybias,
    unsigned short* h1bf, unsigned short* h2bf, float* h2f,
    float* ctxacc, float* lacc, float* c1p, float* c2p,
    float* esc, unsigned int* ctr, float* out)
{
  __shared__ float W1s[1280][8];   // 40 KB: 8 gate1 cols (dims 2bi,2bi+1)
  __shared__ float W2s[768][8];    // 24 KB: 8 gate2 cols (dims 2bi,2bi+1), bi<128
  __shared__ float b1s[8];
  __shared__ float b2s[8];
  __shared__ float embrow[512];
  __shared__ float chb;
  __shared__ float redA[8][8][64];
  __shared__ float g1s[8][64];
  __shared__ float part[2][256];
  __shared__ float e_l[256];
  __shared__ float h2loc[256];

  const int bi = blockIdx.x;
  const int tid = threadIdx.x;
  const int w = tid >> 6;
  const int lane = tid & 63;

  for (int idx = tid; idx < 1280*8; idx += 512){
    int k = idx >> 3, c = idx & 7;
    int col = ((c >> 1) << 9) + 2*bi + (c & 1);
    W1s[k][c] = (k < 768) ? W_ih1[(size_t)k*2048 + col] : W_hh1[(size_t)(k-768)*2048 + col];
  }
  if (bi < 128){
    for (int idx = tid; idx < 768*8; idx += 512){
      int k = idx >> 3, c = idx & 7;
      int col = ((c >> 1) << 8) + 2*bi + (c & 1);
      W2s[k][c] = (k < 512) ? W_ih2[(size_t)k*1024 + col] : W_hh2[(size_t)(k-512)*1024 + col];
    }
    if (tid < 8){ int col = ((tid >> 1) << 8) + 2*bi + (tid & 1); b2s[tid] = b_ih2[col] + b_hh2[col]; }
  }
  if (tid < 8){ int col = ((tid >> 1) << 9) + 2*bi + (tid & 1); b1s[tid] = b_ih1[col] + b_hh1[col]; }
  if (bi >= 128 && bi < 158){
    embrow[tid] = embW[(bi-128)*512 + tid];
    if (tid == 0) chb = char_b[bi-128];
  }
  __syncthreads();

  unsigned int gen = 0;
  const int myb = bi & 63;
  const int sc  = bi >> 6;
  const int mylen = lens[myb];
  const int sbase = sc * 200;

  float* preds = out;            // [64][250][30]
  float* plot  = out + 480000;   // [800][250]

  for (int t = 0; t < 250; ++t){
    const int p  = t & 1;
    const int np = 1 - p;
    const unsigned short* h1p_bf = h1bf + p*(64*512);
    unsigned short*       h1n_bf = h1bf + np*(64*512);
    const unsigned short* h2p_bf = h2bf + p*(64*256);
    unsigned short*       h2n_bf = h2bf + np*(64*256);
    const float* h2f_p = h2f + p*(64*256);
    float*       h2f_np= h2f + np*(64*256);
    const float* ca_p  = ctxacc + p*(64*256);
    float*       ca_np = ctxacc + np*(64*256);
    const float* la_p  = lacc + p*64;
    float*       la_np = lacc + np*64;

    // ---------------- Phase 1: gates1 + LSTM1 (all 256 blocks) ----------------
    {
      float acc[8]  = {0,0,0,0,0,0,0,0};
      float accB[8] = {0,0,0,0,0,0,0,0};
      const int b = lane;
      const int tok = (t == 0) ? 0 : y[b*250 + (t-1)];
      const float* erow = embW + (size_t)tok*512;            // plain cached
      const float* crow = ca_p + b*256 - 512;                // f32 sc1
      const unsigned short* hrow = h1p_bf + b*512 - 768;     // bf16 sc1
      const int k0 = w*160, k1 = k0 + 160;
      const int a1 = MINI(k1, 512);
      for (int k = k0; k < a1; k += 4){
        float4 xv = *(const float4*)(erow + k);
        const float* w0 = W1s[k]; const float* w1 = W1s[k+1];
        const float* w2 = W1s[k+2]; const float* w3 = W1s[k+3];
        #pragma unroll
        for (int cc = 0; cc < 8; cc++)
          acc[cc] += xv.x*w0[cc] + xv.y*w1[cc] + xv.z*w2[cc] + xv.w*w3[cc];
      }
      dot_f32(crow, MAXI(k0,512), MINI(k1,768), W1s, accB);
      dot_bf16(hrow, MAXI(k0,768), k1, W1s, acc);
      const float rl = 1.f / ald1(&la_p[b]);
      #pragma unroll
      for (int c = 0; c < 8; c++) redA[w][c][b] = acc[c] + accB[c]*rl;
    }
    __syncthreads();
    { int c = tid >> 6, b = tid & 63;
      float g = b1s[c];
      #pragma unroll
      for (int ww = 0; ww < 8; ww++) g += redA[ww][c][b];
      g1s[c][b] = g;
    }
    __syncthreads();
    if (w == 0){   // LSTM1 cell: dims 2bi, 2bi+1
      int b = lane;
      float h0, h1v;
      { float gi=g1s[0][b], gf=g1s[2][b], gg=g1s[4][b], go=g1s[6][b];
        float co = c1p[bi*128 + 2*b];
        float cn = sigm(gf)*co + sigm(gi)*tanhf_(gg);
        c1p[bi*128 + 2*b] = cn; h0 = sigm(go)*tanhf_(cn); }
      { float gi=g1s[1][b], gf=g1s[3][b], gg=g1s[5][b], go=g1s[7][b];
        float co = c1p[bi*128 + 2*b + 1];
        float cn = sigm(gf)*co + sigm(gi)*tanhf_(gg);
        c1p[bi*128 + 2*b + 1] = cn; h1v = sigm(go)*tanhf_(cn); }
      unsigned int pk = (unsigned int)f2bf(h0) | ((unsigned int)f2bf(h1v) << 16);
      ast32(h1n_bf + b*512 + 2*bi, pk);
    }
    gbar(ctr, &gen);  // SYNC1: h1 ready

    // ---------------- Phase 2 (split by block role) ----------------
    if (bi < 128){
      // gates2 + LSTM2: dims 2bi, 2bi+1
      {
        float acc2[8] = {0,0,0,0,0,0,0,0};
        const int b = lane;
        const unsigned short* h1r = h1n_bf + b*512;
        const unsigned short* h2r = h2p_bf + b*256 - 512;
        const int k0 = w*96, k1 = k0 + 96;
        dot_bf16(h1r, k0, MINI(k1,512), W2s, acc2);
        dot_bf16(h2r, MAXI(k0,512), k1, W2s, acc2);
        #pragma unroll
        for (int c = 0; c < 8; c++) redA[w][c][lane] = acc2[c];
      }
      __syncthreads();
      { int c = tid >> 6, b = tid & 63;
        float g = b2s[c];
        #pragma unroll
        for (int ww = 0; ww < 8; ww++) g += redA[ww][c][b];
        g1s[c][b] = g;
      }
      __syncthreads();
      if (w == 0){
        int b = lane;
        float h0, h1v;
        { float gi=g1s[0][b], gf=g1s[2][b], gg=g1s[4][b], go=g1s[6][b];
          float co = c2p[bi*128 + 2*b];
          float cn = sigm(gf)*co + sigm(gi)*tanhf_(gg);
          c2p[bi*128 + 2*b] = cn; h0 = sigm(go)*tanhf_(cn); }
        { float gi=g1s[1][b], gf=g1s[3][b], gg=g1s[5][b], go=g1s[7][b];
          float co = c2p[bi*128 + 2*b + 1];
          float cn = sigm(gf)*co + sigm(gi)*tanhf_(gg);
          c2p[bi*128 + 2*b + 1] = cn; h1v = sigm(go)*tanhf_(cn); }
        unsigned int pk = (unsigned int)f2bf(h0) | ((unsigned int)f2bf(h1v) << 16);
        ast32(h2n_bf + b*256 + 2*bi, pk);
        ast2(h2f_np + b*256 + 2*bi, h0, h1v);
      }
    } else if (bi < 158){
      // logits for step t-1
      if (t > 0){
        int b3 = tid & 63, ch = tid >> 6;
        const float* base = (ch < 4) ? (h2f_p + b3*256 + ch*64)
                                     : (ca_p  + b3*256 + (ch-4)*64);
        const float* er = &embrow[(ch < 4) ? ch*64 : 256 + (ch-4)*64];
        float2 v[32];
        #pragma unroll
        for (int i = 0; i < 32; i++) v[i] = ald2(base + 2*i);
        float pc = 0.f;
        #pragma unroll
        for (int i = 0; i < 32; i++) pc += v[i].x*er[2*i] + v[i].y*er[2*i+1];
        if (ch >= 4) pc *= 1.f / ald1(&la_p[b3]);
        g1s[ch][b3] = pc;
        __syncthreads();
        if (tid < 64){
          float s2 = chb;
          #pragma unroll
          for (int c = 0; c < 8; c++) s2 += g1s[c][tid];
          preds[tid*7500 + (t-1)*30 + (bi-128)] = s2;
        }
      }
    } else if (bi < 190){
      if (t > 0 && tid < 25){
        int s3 = (bi-158)*25 + tid;
        plot[(size_t)s3*250 + (t-1)] = ald1(&esc[s3]) * (1.f / ald1(&la_p[0]));
      }
    } else if (bi < 254){
      if (tid < 128) ast2(&ca_np[(bi-190)*256 + 2*tid], 0.f, 0.f);
    } else if (bi == 254){
      if (tid < 64) ast1(&la_np[tid], 0.f);
    }
    gbar(ctr, &gen);  // SYNC2: h2 ready, accumulators zeroed

    // ---------------- Phase 3: attention (all blocks; s-quarter) ----------------
    {
      if (tid < 128){ float2 hv = ald2(&h2f_np[myb*256 + 2*tid]);
                      h2loc[2*tid] = hv.x; h2loc[2*tid+1] = hv.y; }
      __syncthreads();
      const int qlen = MINI(200, MAXI(0, mylen - sbase));
      const int srow = tid & 255, kh = tid >> 8;
      if (srow < qlen){
        const unsigned short* kp = kT + (size_t)myb*204800 + (size_t)(kh*128)*800 + sbase + srow;
        const float* hl = &h2loc[kh*128];
        float pacc = 0.f;
        #pragma unroll 4
        for (int k = 0; k < 128; k++){ pacc += bf2f(*kp)*hl[k]; kp += 800; }
        part[kh][srow] = pacc;
      }
      __syncthreads();
      if (tid < 256){
        float e = 0.f;
        if (tid < qlen) e = __expf(part[0][tid] + part[1][tid] + keybias[myb*800 + sbase + tid]);
        e_l[tid] = e;
        if (myb == 0 && tid < 200) ast1(&esc[sbase + tid], e);
      }
      __syncthreads();
      if (w == 0){
        float s4 = e_l[lane] + e_l[lane+64] + e_l[lane+128] + e_l[lane+192];
        #pragma unroll
        for (int o = 1; o < 64; o <<= 1) s4 += __shfl_xor(s4, o, 64);
        if (lane == 0) aadd(&la_np[myb], s4);
      }
      {
        const int d = tid & 255, rh = tid >> 8;
        const int j0 = rh*100, j1 = MINI(j0+100, qlen);
        float a = 0.f;
        const unsigned short* vp = vl + (size_t)myb*204800 + (size_t)(sbase+j0)*256 + d;
        #pragma unroll 4
        for (int j = j0; j < j1; j++){ a += e_l[j]*bf2f(*vp); vp += 256; }
        part[rh][d] = a;
      }
      __syncthreads();
      if (tid < 256) aadd(&ca_np[myb*256 + tid], part[0][tid] + part[1][tid]);
    }
    gbar(ctr, &gen);  // SYNC3: context accumulated
  }

  // ---------------- epilogue: outputs for step 249 (parity 0 buffers) ----------------
  {
    const float* h2f_p = h2f;        // parity 0
    const float* ca_p  = ctxacc;
    const float* la_p  = lacc;
    if (bi >= 128 && bi < 158){
      int b3 = tid & 63, ch = tid >> 6;
      const float* base = (ch < 4) ? (h2f_p + b3*256 + ch*64)
                                   : (ca_p  + b3*256 + (ch-4)*64);
      const float* er = &embrow[(ch < 4) ? ch*64 : 256 + (ch-4)*64];
      float2 v[32];
      #pragma unroll
      for (int i = 0; i < 32; i++) v[i] = ald2(base + 2*i);
      float pc = 0.f;
      #pragma unroll
      for (int i = 0; i < 32; i++) pc += v[i].x*er[2*i] + v[i].y*er[2*i+1];
      if (ch >= 4) pc *= 1.f / ald1(&la_p[b3]);
      g1s[ch][b3] = pc;
      __syncthreads();
      if (tid < 64){
        float s2 = chb;
        #pragma unroll
        for (int c = 0; c < 8; c++) s2 += g1s[c][tid];
        preds[tid*7500 + 249*30 + (bi-128)] = s2;
      }
    } else if (bi >= 158 && bi < 190){
      if (tid < 25){
        int s3 = (bi-158)*25 + tid;
        plot[(size_t)s3*250 + 249] = ald1(&esc[s3]) * (1.f / ald1(&la_p[0]));
      }
    }
  }
}

// ---------------------------------------------------------------------------
extern "C" void kernel_launch(void* const* d_in, const int* in_sizes, int n_in,
                              void* d_out, int out_size, void* d_ws, size_t ws_size,
                              hipStream_t stream){
  const float* enc    = (const float*)d_in[0];
  const float* embW   = (const float*)d_in[1];
  const float* W_ih1  = (const float*)d_in[2];
  const float* b_ih1  = (const float*)d_in[3];
  const float* W_hh1  = (const float*)d_in[4];
  const float* b_hh1  = (const float*)d_in[5];
  const float* W_ih2  = (const float*)d_in[6];
  const float* b_ih2  = (const float*)d_in[7];
  const float* W_hh2  = (const float*)d_in[8];
  const float* b_hh2  = (const float*)d_in[9];
  const float* Wk     = (const float*)d_in[10];
  const float* bk     = (const float*)d_in[11];
  const float* Wv     = (const float*)d_in[12];
  const float* bv     = (const float*)d_in[13];
  const float* Wq     = (const float*)d_in[14];
  const float* bq     = (const float*)d_in[15];
  const float* char_b = (const float*)d_in[16];
  const int*   lens   = (const int*)d_in[17];
  const int*   y      = (const int*)d_in[18];

  char* ws = (char*)d_ws;
  unsigned short* kT   = (unsigned short*)(ws + 0);          // 26,214,400
  unsigned short* vlp  = (unsigned short*)(ws + 26214400);   // 26,214,400
  float* keybias       = (float*)(ws + 52428800);            //    204,800
  unsigned short* Bmat = (unsigned short*)(ws + 52633600);   //    524,288
  float* bvec          = (float*)(ws + 53157888);            //      2,048
  float* wkb           = (float*)(ws + 53159936);            //      2,048
  float* cb0           = (float*)(ws + 53161984);            //      1,024
  unsigned short* h1bf = (unsigned short*)(ws + 53163008);   //    131,072 (2 bufs)
  unsigned short* h2bf = (unsigned short*)(ws + 53294080);   //     65,536 (2 bufs)
  float* h2f           = (float*)(ws + 53359616);            //    262,144 (2 bufs)
  float* ctxacc        = (float*)(ws + 53621760);            //    131,072 (2 bufs)
  float* lacc          = (float*)(ws + 53752832);            //      1,024 (2 bufs)
  float* c1p           = (float*)(ws + 53753856);            //    131,072
  float* c2p           = (float*)(ws + 53884928);            //     65,536
  float* esc           = (float*)(ws + 53950464);            //      4,096
  unsigned int* ctr    = (unsigned int*)(ws + 53954560);     //      4,096
  float* out = (float*)d_out;

  k_prepw<<<512, 256, 0, stream>>>(Wk, Wq, Wv, bk, bq, bv, Bmat, bvec, wkb, cb0);
  k_keybias<<<6400, 512, 0, stream>>>(enc, wkb, cb0, keybias);
  k_init<<<64, 256, 0, stream>>>(enc, Wk, bk, ctxacc, lacc, h1bf, h2bf, h2f, c1p, c2p, ctr);
  k_gemm<<<6400, 256, 0, stream>>>(enc, Bmat, bvec, kT, vlp);
  k_decode<<<256, 512, 0, stream>>>(W_ih1, b_ih1, W_hh1, b_hh1, W_ih2, b_ih2, W_hh2, b_hh2,
                                    embW, char_b, lens, y, kT, vlp, keybias,
                                    h1bf, h2bf, h2f, ctxacc, lacc, c1p, c2p, esc, ctr, out);
}